// Round 1
// baseline (1654.378 us; speedup 1.0000x reference)
//
#include <hip/hip_runtime.h>

#define GRP 8
#define SUBD 64
#define NCODE 1024
#define TLEN 4096
#define NBATCH 8
#define NVEC (NBATCH * TLEN)          // 32768
#define QOUT (NBATCH * 512 * TLEN)    // 16777216

// ws layout:
// [0]                : double lossAcc[2]
// [16]               : float e2[2*GRP*NCODE]   (cb1 then cb2)  = 65536 B
// [16+65536]         : int idx1[GRP*NVEC]                      = 1 MB
// [16+65536+1048576] : int idx2[GRP*NVEC]                      = 1 MB

__global__ __launch_bounds__(256) void k_e2(const float* __restrict__ cb1,
                                            const float* __restrict__ cb2,
                                            float* __restrict__ e2) {
    int i = blockIdx.x * 256 + threadIdx.x;      // 0 .. 16383
    const float* c = (i < GRP * NCODE) ? (cb1 + (size_t)i * SUBD)
                                       : (cb2 + (size_t)(i - GRP * NCODE) * SUBD);
    float s = 0.f;
#pragma unroll
    for (int d = 0; d < SUBD; ++d) s = __builtin_fmaf(c[d], c[d], s);
    e2[i] = s;
}

// Scan 1024 codes; xe = ascending-d fp32 fma chain (one accumulator per code),
// d = fl(fl(x2 + e2k) - 2*xe).  Strict < keeps the FIRST minimum (np.argmin ties).
__device__ __forceinline__ void argmin1024(const float* __restrict__ cg,
                                           const float* __restrict__ e2g,
                                           const float (&r)[SUBD], float x2,
                                           int& bidx) {
    float best = 1e30f;
    bidx = 0;
    for (int k = 0; k < NCODE; k += 2) {
        const float* __restrict__ c0 = cg + (size_t)k * SUBD;
        const float* __restrict__ c1 = c0 + SUBD;
        float a0 = 0.f, a1 = 0.f;
#pragma unroll
        for (int d = 0; d < SUBD; ++d) {
            a0 = __builtin_fmaf(c0[d], r[d], a0);
            a1 = __builtin_fmaf(c1[d], r[d], a1);
        }
        float t0 = x2 + e2g[k];
        float d0 = t0 - 2.0f * a0;     // == fl(t0 - fl(2*a0)); 2*a0 exact
        float t1 = x2 + e2g[k + 1];
        float d1 = t1 - 2.0f * a1;
        if (d0 < best) { best = d0; bidx = k; }
        if (d1 < best) { best = d1; bidx = k + 1; }
    }
}

__device__ __forceinline__ void block_reduce_atomic(double v, double* target) {
    for (int off = 32; off; off >>= 1) v += __shfl_down(v, off, 64);
    __shared__ double ws[4];
    int lane = threadIdx.x & 63, w = threadIdx.x >> 6;
    if (lane == 0) ws[w] = v;
    __syncthreads();
    if (threadIdx.x == 0) {
        atomicAdd(target, ws[0] + ws[1] + ws[2] + ws[3]);
    }
}

__global__ __launch_bounds__(256) void k_stage1(const float* __restrict__ x,
                                                const float* __restrict__ cb1,
                                                const float* __restrict__ e2,
                                                int* __restrict__ idx1,
                                                float* __restrict__ outIdx) {
    int t = blockIdx.x * 256 + threadIdx.x;
    int g = blockIdx.y, b = blockIdx.z;
    const float* xp = x + ((size_t)(b * 512 + g * SUBD)) * TLEN + t;
    float r[SUBD];
#pragma unroll
    for (int d = 0; d < SUBD; ++d) r[d] = xp[(size_t)d * TLEN];
    float x2 = 0.f;
#pragma unroll
    for (int d = 0; d < SUBD; ++d) x2 = __builtin_fmaf(r[d], r[d], x2);
    int bi;
    argmin1024(cb1 + (size_t)g * NCODE * SUBD, e2 + g * NCODE, r, x2, bi);
    int n = b * TLEN + t;
    idx1[g * NVEC + n] = bi;
    outIdx[(size_t)g * NVEC + n] = (float)bi;    // stage-1 rows 0..7
}

__global__ __launch_bounds__(256) void k_stage2(const float* __restrict__ x,
                                                const float* __restrict__ cb1,
                                                const float* __restrict__ cb2,
                                                const float* __restrict__ e2_2,
                                                const int* __restrict__ idx1,
                                                int* __restrict__ idx2,
                                                float* __restrict__ outIdx,
                                                double* __restrict__ lossAcc) {
    int t = blockIdx.x * 256 + threadIdx.x;
    int g = blockIdx.y, b = blockIdx.z;
    int n = b * TLEN + t;
    const float* xp = x + ((size_t)(b * 512 + g * SUBD)) * TLEN + t;
    float r[SUBD];
#pragma unroll
    for (int d = 0; d < SUBD; ++d) r[d] = xp[(size_t)d * TLEN];

    int i1 = idx1[g * NVEC + n];
    const float4* z4 = (const float4*)(cb1 + ((size_t)g * NCODE + i1) * SUBD);
    double ls = 0.0;
#pragma unroll
    for (int j = 0; j < SUBD / 4; ++j) {
        float4 zv = z4[j];
#pragma unroll
        for (int i = 0; i < 4; ++i) {
            int d = 4 * j + i;
            float z = (&zv.x)[i];
            float tt = z - r[d];          // fl(z - r)   (loss term, exact ref expr)
            float zst = r[d] + tt;        // fl(r + fl(z - r))
            float sq = tt * tt;
            ls += (double)sq;
            r[d] = r[d] - zst;            // fl(r - z_st) -> residual2 bit-exact
        }
    }
    float x2 = 0.f;
#pragma unroll
    for (int d = 0; d < SUBD; ++d) x2 = __builtin_fmaf(r[d], r[d], x2);
    int bi;
    argmin1024(cb2 + (size_t)g * NCODE * SUBD, e2_2 + g * NCODE, r, x2, bi);
    idx2[g * NVEC + n] = bi;
    outIdx[(size_t)g * NVEC + n] = (float)bi;    // stage-2 rows 8..15
    block_reduce_atomic(ls, lossAcc + 0);
}

__global__ __launch_bounds__(256) void k_out(const float* __restrict__ x,
                                             const float* __restrict__ cb1,
                                             const float* __restrict__ cb2,
                                             const int* __restrict__ idx1,
                                             const int* __restrict__ idx2,
                                             float* __restrict__ qout,
                                             double* __restrict__ lossAcc) {
    int t = blockIdx.x * 256 + threadIdx.x;
    int g = blockIdx.y, b = blockIdx.z;
    int n = b * TLEN + t;
    int i1 = idx1[g * NVEC + n];
    int i2 = idx2[g * NVEC + n];
    const float4* z1v = (const float4*)(cb1 + ((size_t)g * NCODE + i1) * SUBD);
    const float4* z2v = (const float4*)(cb2 + ((size_t)g * NCODE + i2) * SUBD);
    const float* xp = x + ((size_t)(b * 512 + g * SUBD)) * TLEN + t;
    float* op = qout + ((size_t)(b * 512 + g * SUBD)) * TLEN + t;
    double ls = 0.0;
#pragma unroll
    for (int j = 0; j < SUBD / 4; ++j) {
        float4 a = z1v[j];
        float4 c = z2v[j];
#pragma unroll
        for (int i = 0; i < 4; ++i) {
            int d = 4 * j + i;
            float r = xp[(size_t)d * TLEN];
            float z1 = (&a.x)[i];
            float z2 = (&c.x)[i];
            float t1 = z1 - r;
            float zst1 = r + t1;
            float r2 = r - zst1;
            float t2 = z2 - r2;           // fl(z2 - residual2) (loss term)
            float zst2 = r2 + t2;
            float q = zst1 + zst2;        // quantized = fl(z_st1 + z_st2)
            op[(size_t)d * TLEN] = q;
            float sq = t2 * t2;
            ls += (double)sq;
        }
    }
    block_reduce_atomic(ls, lossAcc + 1);
}

__global__ void k_final(float* __restrict__ lossOut, const double* __restrict__ lossAcc) {
    // loss_i = 1.0*m_i + 0.25*m_i = 1.25*m_i ; total = (l1+l2)/2 = 0.625*(m1+m2)
    double m = (lossAcc[0] + lossAcc[1]) / (double)QOUT;
    lossOut[0] = (float)(0.625 * m);
}

extern "C" void kernel_launch(void* const* d_in, const int* in_sizes, int n_in,
                              void* d_out, int out_size, void* d_ws, size_t ws_size,
                              hipStream_t stream) {
    const float* x   = (const float*)d_in[0];
    const float* cb1 = (const float*)d_in[1];
    const float* cb2 = (const float*)d_in[2];
    float* out = (float*)d_out;

    char* ws = (char*)d_ws;
    double* lossAcc = (double*)ws;
    float* e2   = (float*)(ws + 16);                        // 16384 floats
    int*   idx1 = (int*)(ws + 16 + 65536);
    int*   idx2 = (int*)(ws + 16 + 65536 + 1048576);

    hipMemsetAsync(ws, 0, 16, stream);

    k_e2<<<dim3(64), dim3(256), 0, stream>>>(cb1, cb2, e2);

    dim3 grid(TLEN / 256, GRP, NBATCH);
    float* outIdx = out + QOUT + 1;
    k_stage1<<<grid, dim3(256), 0, stream>>>(x, cb1, e2, idx1, outIdx);
    k_stage2<<<grid, dim3(256), 0, stream>>>(x, cb1, cb2, e2 + GRP * NCODE,
                                             idx1, idx2, outIdx + (size_t)GRP * NVEC, lossAcc);
    k_out<<<grid, dim3(256), 0, stream>>>(x, cb1, cb2, idx1, idx2, out, lossAcc);
    k_final<<<1, 1, 0, stream>>>(out + QOUT, lossAcc);
}